// Round 1
// baseline (121.852 us; speedup 1.0000x reference)
//
#include <hip/hip_runtime.h>

// Problem constants (fixed by setup_inputs): B=256, J=17, H*W=3072.
#define HW        3072
#define N_TOTAL   (256 * 17 * 3072)       // 13,369,344 elements
#define N_VEC4    (N_TOTAL / 4)           // 3,342,336 float4s
#define NBLOCKS   1024
#define BLOCK     256

// Kernel 1: grid-stride float4 weighted-SSE partial reduction.
// acc += tw[b,j]^2 * (o - t)^2 summed over the 4 lanes of each float4.
// float4 index i -> flat (b,j) index = (4*i)/3072 = i/768 (3072 % 4 == 0,
// so a float4 never straddles a joint boundary).
__global__ __launch_bounds__(BLOCK) void partial_sse_kernel(
    const float* __restrict__ out,
    const float* __restrict__ tgt,
    const float* __restrict__ tw,
    float* __restrict__ partials)
{
    const float4* o4 = (const float4*)out;
    const float4* t4 = (const float4*)tgt;

    int tid    = blockIdx.x * BLOCK + threadIdx.x;
    int stride = gridDim.x * BLOCK;

    float acc = 0.0f;
    for (int i = tid; i < N_VEC4; i += stride) {
        float4 o = o4[i];
        float4 t = t4[i];
        float  w = tw[i / 768];          // L1/L2-resident, broadcast-ish
        float  w2 = w * w;
        float d0 = o.x - t.x;
        float d1 = o.y - t.y;
        float d2 = o.z - t.z;
        float d3 = o.w - t.w;
        acc += w2 * (d0 * d0 + d1 * d1 + d2 * d2 + d3 * d3);
    }

    // wave64 shuffle reduction
    #pragma unroll
    for (int off = 32; off > 0; off >>= 1)
        acc += __shfl_down(acc, off, 64);

    __shared__ float lds[BLOCK / 64];
    int lane = threadIdx.x & 63;
    int wave = threadIdx.x >> 6;
    if (lane == 0) lds[wave] = acc;
    __syncthreads();

    if (threadIdx.x == 0) {
        float s = 0.0f;
        #pragma unroll
        for (int w_i = 0; w_i < BLOCK / 64; ++w_i) s += lds[w_i];
        partials[blockIdx.x] = s;
    }
}

// Kernel 2: reduce NBLOCKS partials, scale, write the scalar loss.
__global__ __launch_bounds__(BLOCK) void final_reduce_kernel(
    const float* __restrict__ partials,
    float* __restrict__ out)
{
    float acc = 0.0f;
    for (int i = threadIdx.x; i < NBLOCKS; i += BLOCK)
        acc += partials[i];

    #pragma unroll
    for (int off = 32; off > 0; off >>= 1)
        acc += __shfl_down(acc, off, 64);

    __shared__ float lds[BLOCK / 64];
    int lane = threadIdx.x & 63;
    int wave = threadIdx.x >> 6;
    if (lane == 0) lds[wave] = acc;
    __syncthreads();

    if (threadIdx.x == 0) {
        float s = 0.0f;
        #pragma unroll
        for (int w_i = 0; w_i < BLOCK / 64; ++w_i) s += lds[w_i];
        out[0] = 0.5f * s / (float)N_TOTAL;
    }
}

extern "C" void kernel_launch(void* const* d_in, const int* in_sizes, int n_in,
                              void* d_out, int out_size, void* d_ws, size_t ws_size,
                              hipStream_t stream)
{
    const float* output = (const float*)d_in[0];   // [256,17,64,48] f32
    const float* target = (const float*)d_in[1];   // [256,17,64,48] f32
    const float* tw     = (const float*)d_in[2];   // [256,17,1]     f32

    float* partials = (float*)d_ws;                // NBLOCKS floats (4 KB)

    partial_sse_kernel<<<NBLOCKS, BLOCK, 0, stream>>>(output, target, tw, partials);
    final_reduce_kernel<<<1, BLOCK, 0, stream>>>(partials, (float*)d_out);
}